// Round 10
// baseline (249.514 us; speedup 1.0000x reference)
//
#include <hip/hip_runtime.h>
#include <hip/hip_bf16.h>
#include <math.h>

#define N 8192
#define ZD 128
#define NTILE 64            // N / 128
#define NUPPER 2080         // NTILE*(NTILE+1)/2  (= 8 * 260, divisible by 8)
#define AROW 136            // f16 per padded LDS row (272 B, 16B-aligned rows)

typedef __attribute__((ext_vector_type(8))) _Float16 f16x8;
typedef __attribute__((ext_vector_type(4))) float f32x4;

__device__ __forceinline__ int tri_cum(int ti) {   // tiles before row ti
    return (ti * (2 * NTILE + 1 - ti)) / 2;
}

__device__ __forceinline__ void tile_decode(int t, int& ti, int& tj) {
    int est = (int)((129.0f - sqrtf(16641.0f - 8.0f * (float)t)) * 0.5f);
    if (est < 0) est = 0;
    while (tri_cum(est) > t) --est;
    while (tri_cum(est + 1) <= t) ++est;
    ti = est;
    tj = est + (t - tri_cum(est));
}

// ---------------------------------------------------------------------------
// k1: Z = relu(h @ W1 + b1) @ W2 + b2 (fp32 math), stored as f16.
// ---------------------------------------------------------------------------
__global__ __launch_bounds__(256) void k1_mlp(
    const float* __restrict__ h, const float* __restrict__ W1,
    const float* __restrict__ b1, const float* __restrict__ W2,
    const float* __restrict__ b2, _Float16* __restrict__ Zf)
{
    __shared__ float W1s[64][65];
    __shared__ float W2s[64][129];
    __shared__ float hs[32][68];
    __shared__ float Ts[32][68];
    __shared__ float b1s[64];
    __shared__ float b2s[128];
    const int tid = threadIdx.x;
    const int row0 = blockIdx.x * 32;

    for (int e = tid; e < 64 * 64; e += 256) W1s[e >> 6][e & 63] = W1[e];
    for (int e = tid; e < 64 * 128; e += 256) W2s[e >> 7][e & 127] = W2[e];
    for (int e = tid; e < 32 * 64; e += 256) hs[e >> 6][e & 63] = h[(size_t)row0 * 64 + e];
    if (tid < 64) b1s[tid] = b1[tid];
    if (tid < 128) b2s[tid] = b2[tid];
    __syncthreads();

    {
        const int c = tid & 63;
        const int r0 = (tid >> 6) * 8;
        float s[8];
        #pragma unroll
        for (int j = 0; j < 8; ++j) s[j] = b1s[c];
        #pragma unroll
        for (int k0 = 0; k0 < 64; k0 += 4) {
            const float w0 = W1s[k0 + 0][c], w1 = W1s[k0 + 1][c];
            const float w2 = W1s[k0 + 2][c], w3 = W1s[k0 + 3][c];
            #pragma unroll
            for (int j = 0; j < 8; ++j) {
                f32x4 hv = *(const f32x4*)&hs[r0 + j][k0];
                s[j] = fmaf(hv[0], w0, s[j]);
                s[j] = fmaf(hv[1], w1, s[j]);
                s[j] = fmaf(hv[2], w2, s[j]);
                s[j] = fmaf(hv[3], w3, s[j]);
            }
        }
        #pragma unroll
        for (int j = 0; j < 8; ++j) Ts[r0 + j][c] = fmaxf(s[j], 0.0f);
    }
    __syncthreads();
    {
        const int c = tid & 127;
        const int r0 = (tid >> 7) * 16;
        float s[16];
        #pragma unroll
        for (int j = 0; j < 16; ++j) s[j] = b2s[c];
        #pragma unroll
        for (int k0 = 0; k0 < 64; k0 += 4) {
            const float w0 = W2s[k0 + 0][c], w1 = W2s[k0 + 1][c];
            const float w2 = W2s[k0 + 2][c], w3 = W2s[k0 + 3][c];
            #pragma unroll
            for (int j = 0; j < 16; ++j) {
                f32x4 tv = *(const f32x4*)&Ts[r0 + j][k0];
                s[j] = fmaf(tv[0], w0, s[j]);
                s[j] = fmaf(tv[1], w1, s[j]);
                s[j] = fmaf(tv[2], w2, s[j]);
                s[j] = fmaf(tv[3], w3, s[j]);
            }
        }
        #pragma unroll
        for (int j = 0; j < 16; ++j)
            Zf[(size_t)(row0 + r0 + j) * ZD + c] = (_Float16)s[j];
    }
}

// ---------------------------------------------------------------------------
// k3: 2080 upper tiles, XCD-swizzled, 128x128 per block, 4 waves, 2 blocks/CU.
// LDS-staged f16 MFMA GEMM; register-direct epilogue (no T buffer):
//   logits[i,j] = 4 scalar nt-stores/fragment (64B sectors),
//   logits[j,i] = 1 f32x4 nt-store/fragment (64B sectors, bit-exact symmetric),
//   noise scalar nt-loads, v quantized to u8: packed u32 -> vT (c-major) and
//   bytes -> vTT (r-major), both aliased over the A-stage LDS.
// ONE heavy barrier, then coalesced u32 flush of vfull [i,j] and [j,i].
// No sums here (kE computes them from vfull).
// ---------------------------------------------------------------------------
__global__ __launch_bounds__(256, 2) void k3_main(
    const _Float16* __restrict__ Zf, const float* __restrict__ noise,
    float* __restrict__ logits, unsigned char* __restrict__ vfull)
{
    int ti, tj;
    const int t = (blockIdx.x & 7) * (NUPPER / 8) + (blockIdx.x >> 3);  // XCD swizzle
    tile_decode(t, ti, tj);
    const bool diag = (ti == tj);

    __shared__ _Float16 smem[2 * 128 * AROW];               // 69632 B
    _Float16* As = smem;                                     // [128][AROW]
    _Float16* Bs = smem + 128 * AROW;
    unsigned char* vTT = (unsigned char*)smem;               // [128 r][132 c] bytes (A region)
    unsigned char* vT  = (unsigned char*)(smem + 128 * AROW);// [128 c][132 r] bytes (B region)

    const int tid = threadIdx.x;
    const int lane = tid & 63;
    const int w = tid >> 6;
    const int wr = w >> 1, wc = w & 1;
    const int fr = lane & 15;
    const int kg = lane >> 4;
    const int i0 = ti * 128, j0 = tj * 128;

    // ---- stage A,B into LDS (single Zf read per block) ----
    #pragma unroll
    for (int p = 0; p < 8; ++p) {
        const int c = tid + p * 256;
        const int row = c >> 4, cg = (c & 15) << 3;
        *(f16x8*)&As[row * AROW + cg] = *(const f16x8*)(Zf + (size_t)(i0 + row) * ZD + cg);
        *(f16x8*)&Bs[row * AROW + cg] = *(const f16x8*)(Zf + (size_t)(j0 + row) * ZD + cg);
    }
    __syncthreads();   // cheap: only stage traffic outstanding

    f32x4 acc[4][4];
    #pragma unroll
    for (int mf = 0; mf < 4; ++mf)
        #pragma unroll
        for (int nf = 0; nf < 4; ++nf)
            acc[mf][nf] = (f32x4)0.0f;

    #pragma unroll
    for (int kc = 0; kc < 4; ++kc) {
        const int ko = kc * 32 + kg * 8;
        f16x8 a[4], b[4];
        #pragma unroll
        for (int mf = 0; mf < 4; ++mf) {
            a[mf] = *(const f16x8*)&As[(wr * 64 + mf * 16 + fr) * AROW + ko];
            b[mf] = *(const f16x8*)&Bs[(wc * 64 + mf * 16 + fr) * AROW + ko];
        }
        #pragma unroll
        for (int mf = 0; mf < 4; ++mf)
            #pragma unroll
            for (int nf = 0; nf < 4; ++nf)
                acc[mf][nf] = __builtin_amdgcn_mfma_f32_16x16x32_f16(a[mf], b[nf], acc[mf][nf], 0, 0, 0);
    }
    __syncthreads();   // cheap: GEMM LDS reads done; safe to overwrite with vT/vTT

    // ---- register-direct epilogue ----
    #pragma unroll
    for (int mf = 0; mf < 4; ++mf) {
        #pragma unroll
        for (int nf = 0; nf < 4; ++nf) {
            const int Rl = wr * 64 + mf * 16 + (lane >> 4) * 4;   // local rows Rl..Rl+3
            const int Cl = wc * 64 + nf * 16 + (lane & 15);       // local col
            const f32x4 Lv = acc[mf][nf];
            const size_t gi = (size_t)(i0 + Rl) * N + (j0 + Cl);
            #pragma unroll
            for (int k = 0; k < 4; ++k)
                __builtin_nontemporal_store(Lv[k], &logits[gi + (size_t)k * N]);
            __builtin_nontemporal_store(Lv, (f32x4*)&logits[(size_t)(j0 + Cl) * N + (i0 + Rl)]);
            unsigned q = 0;
            #pragma unroll
            for (int k = 0; k < 4; ++k) {
                float u = __builtin_nontemporal_load(&noise[gi + (size_t)k * N]);
                float eps = fmaf(-0.9998f, u, 0.9999f);   // eps in [1e-4, 1-1e-4]
                float om  = fmaf( 0.9998f, u, 0.0001f);   // 1 - eps
                float gate = __logf(eps) - __logf(om) + Lv[k];
                float v = 1.0f / (1.0f + __expf(-gate));
                if (diag && (Rl + k) >= Cl) v = 0.0f;     // strict upper only
                q |= ((unsigned)(int)rintf(v * 255.0f)) << (8 * k);
            }
            *(unsigned*)&vT[Cl * 132 + Rl] = q;           // 4 row-bytes of col Cl
            #pragma unroll
            for (int k = 0; k < 4; ++k)
                vTT[(Rl + k) * 132 + Cl] = (unsigned char)((q >> (8 * k)) & 255);
        }
    }

    __syncthreads();   // the ONE heavy drain (logits stores + noise loads + LDS)

    // ---- coalesced vfull flush ----
    if (!diag) {
        #pragma unroll
        for (int it = 0; it < 16; ++it) {
            const int idx = tid + it * 256;        // 0..4095
            const int r = idx >> 5;
            const int c4 = (idx & 31) * 4;
            const unsigned q = *(const unsigned*)&vTT[r * 132 + c4];
            __builtin_nontemporal_store(q, (unsigned*)&vfull[(size_t)(i0 + r) * N + j0 + c4]);
        }
        #pragma unroll
        for (int it = 0; it < 16; ++it) {
            const int idx = tid + it * 256;
            const int c = idx >> 5;
            const int r4 = (idx & 31) * 4;
            const unsigned q = *(const unsigned*)&vT[c * 132 + r4];
            __builtin_nontemporal_store(q, (unsigned*)&vfull[(size_t)(j0 + c) * N + i0 + r4]);
        }
    } else {
        // symmetric merge within the diagonal tile: byte(r,c) = v(min,max)
        #pragma unroll
        for (int it = 0; it < 16; ++it) {
            const int idx = tid + it * 256;
            const int r = idx >> 5;
            const int c4 = (idx & 31) * 4;
            unsigned q = 0;
            #pragma unroll
            for (int e = 0; e < 4; ++e) {
                const int c = c4 + e;
                unsigned char b = (unsigned char)(vTT[r * 132 + c] | vTT[c * 132 + r]);
                q |= ((unsigned)b) << (8 * e);
            }
            __builtin_nontemporal_store(q, (unsigned*)&vfull[(size_t)(i0 + r) * N + j0 + c4]);
        }
    }
}

// ---------------------------------------------------------------------------
// kE: dvec[i] = rsqrt(1 + rowsum(vfull[i,:])/255). One wave per row.
// vfull is symmetric, so row sums == col sums.
// ---------------------------------------------------------------------------
__global__ __launch_bounds__(256) void kE_sums(
    const unsigned char* __restrict__ vfull, float* __restrict__ dvec)
{
    const int row = blockIdx.x * 4 + (threadIdx.x >> 6);
    const int lane = threadIdx.x & 63;
    const unsigned* p = (const unsigned*)(vfull + (size_t)row * N);
    unsigned s = 0;
    #pragma unroll 8
    for (int k = 0; k < 32; ++k) {
        const unsigned q = __builtin_nontemporal_load(p + lane + k * 64);
        s += (q & 255) + ((q >> 8) & 255) + ((q >> 16) & 255) + (q >> 24);
    }
    #pragma unroll
    for (int off = 32; off >= 1; off >>= 1) s += __shfl_xor((int)s, off);
    if (lane == 0) dvec[row] = rsqrtf(1.0f + (float)s * (1.0f / 255.0f));
}

// ---------------------------------------------------------------------------
// k5: flat streaming normalize (u32 read -> f32x4 write, both coalesced).
// ---------------------------------------------------------------------------
__global__ __launch_bounds__(256) void k5_norm(
    const unsigned char* __restrict__ vfull, float* __restrict__ adj,
    const float* __restrict__ dvec)
{
    const unsigned CHUNKS_PER_ROW = N / 4;               // 2048
    const unsigned stride = gridDim.x * 256;
    const float inv255 = 1.0f / 255.0f;

    for (unsigned idx = blockIdx.x * 256 + threadIdx.x; idx < (unsigned)(N / 4) * N;
         idx += stride) {
        const unsigned row = idx / CHUNKS_PER_ROW;
        const unsigned col4 = (idx % CHUNKS_PER_ROW) * 4;
        const unsigned q = __builtin_nontemporal_load((const unsigned*)&vfull[(size_t)idx * 4]);
        const float sdi = dvec[row] * inv255;
        const f32x4 d4 = *(const f32x4*)&dvec[col4];
        f32x4 o;
        o[0] = (float)(q & 255)         * sdi * d4[0];
        o[1] = (float)((q >> 8) & 255)  * sdi * d4[1];
        o[2] = (float)((q >> 16) & 255) * sdi * d4[2];
        o[3] = (float)(q >> 24)         * sdi * d4[3];
        if (row - col4 < 4u) {
            const float di = dvec[row];
            o[row - col4] = di * di;
        }
        __builtin_nontemporal_store(o, (f32x4*)&adj[(size_t)idx * 4]);
    }
}

// ---------------------------------------------------------------------------
extern "C" void kernel_launch(void* const* d_in, const int* in_sizes, int n_in,
                              void* d_out, int out_size, void* d_ws, size_t ws_size,
                              hipStream_t stream)
{
    const float* h     = (const float*)d_in[0];
    const float* W1    = (const float*)d_in[1];
    const float* b1    = (const float*)d_in[2];
    const float* W2    = (const float*)d_in[3];
    const float* b2    = (const float*)d_in[4];
    const float* noise = (const float*)d_in[5];

    float* adj    = (float*)d_out;                 // output 0: adj_norm [N,N]
    float* logits = adj + (size_t)N * N;           // output 1: adj_logits [N,N]

    _Float16* Zf         = (_Float16*)d_ws;                        // 2 MiB
    unsigned char* vfull = (unsigned char*)(Zf + (size_t)N * ZD);  // [N,N] u8 = 64 MiB
    float* dvec          = (float*)(vfull + (size_t)N * N);        // [N]

    k1_mlp<<<256, 256, 0, stream>>>(h, W1, b1, W2, b2, Zf);
    k3_main<<<NUPPER, 256, 0, stream>>>(Zf, noise, logits, vfull);
    kE_sums<<<N / 4, 256, 0, stream>>>(vfull, dvec);
    k5_norm<<<4096, 256, 0, stream>>>(vfull, adj, dvec);
}